// Round 8
// baseline (123.522 us; speedup 1.0000x reference)
//
#include <hip/hip_runtime.h>

// ---------------------------------------------------------------------------
// BetterGooLayer R8: fully fused sim — phases A and B eliminated.
// R7 post-mortem: phaseA pinned at ~50us across 4 different implementations
// (coalesced vs scattered identical) while re-reading the same 134 MB that
// phaseC reads. Fix is structural: one block per (b,m) owns all 8 chains;
// the cross-chunk scan (old phaseB) becomes a 64-lane f64 Kogge-Stone in-block.
// Inputs read ONCE. rec d-reduction accumulates in LDS across the chain loop.
// Window math / octet KS / f64 rebase cadence identical to R5-R7 (absmax 8).
// ---------------------------------------------------------------------------

#define NS    8192
#define BB    4
#define MM    64
#define DD    8
#define NF    8
#define FL    256
#define CHUNKS 64
#define DAMP  0.9998f
#define SEG   2048

#define REC_OFF  0
#define DISP_OFF (BB*MM*NS)                 // 2097152
#define HF_OFF   (DISP_OFF + BB*MM*DD*NS)   // 18874368

#define SW(i) ((i) + ((i) >> 5))
#define P_SWZ(p) (((p) & ~15) | (((((p) >> 2) ^ ((p) >> 5)) & 3) << 2) | ((p) & 3))

struct Mat { float a, b, c, d; };
__device__ __forceinline__ Mat matmul(Mat x, Mat y) {
    Mat r;
    r.a = fmaf(x.a, y.a, x.b * y.c);
    r.b = fmaf(x.a, y.b, x.b * y.d);
    r.c = fmaf(x.c, y.a, x.d * y.c);
    r.d = fmaf(x.c, y.b, x.d * y.d);
    return r;
}
struct MatD { double a, b, c, d; };
__device__ __forceinline__ MatD matmuld(MatD x, MatD y) {
    MatD r;
    r.a = fma(x.a, y.a, x.b * y.c);
    r.b = fma(x.a, y.b, x.b * y.d);
    r.c = fma(x.c, y.a, x.d * y.c);
    r.d = fma(x.c, y.b, x.d * y.d);
    return r;
}

// ---------------- threefry2x32 (JAX, partitionable counters) ----------------
__device__ __forceinline__ unsigned rotl32(unsigned x, int r) {
    return (x << r) | (x >> (32 - r));
}
__device__ float jax_noise(unsigned idx) {
    const unsigned ks0 = 0u;
    const unsigned ks1 = 123u;
    const unsigned ks2 = 0x1BD11BDAu ^ 0u ^ 123u;
    unsigned x0 = 0u  + ks0;
    unsigned x1 = idx + ks1;
#define TF_RND(r) { x0 += x1; x1 = rotl32(x1, r); x1 ^= x0; }
    TF_RND(13) TF_RND(15) TF_RND(26) TF_RND(6)
    x0 += ks1; x1 += ks2 + 1u;
    TF_RND(17) TF_RND(29) TF_RND(16) TF_RND(24)
    x0 += ks2; x1 += ks0 + 2u;
    TF_RND(13) TF_RND(15) TF_RND(26) TF_RND(6)
    x0 += ks0; x1 += ks1 + 3u;
    TF_RND(17) TF_RND(29) TF_RND(16) TF_RND(24)
    x0 += ks1; x1 += ks2 + 4u;
    TF_RND(13) TF_RND(15) TF_RND(26) TF_RND(6)
    x0 += ks2; x1 += ks0 + 5u;
#undef TF_RND
    unsigned bits = x0 ^ x1;
    float u = __uint_as_float((bits >> 9) | 0x3f800000u) - 1.0f;  // [0,1)
    return fmaxf(-0.01f, u * 0.02f - 0.01f);
}

// ---------------- fused sim: one block per (b,m), 1024 threads --------------
// half = tid>>9 processes chains d = 2*it+half, it=0..3.
// Per chain: wave-local transpose -> 16-step window walk -> octet f32 KS ->
// 64-lane f64 KS chunk scan (wave 0 of half) -> exact re-walk.
__global__ __launch_bounds__(1024) void sim_fused(
    const float* __restrict__ forces, const float* __restrict__ hm,
    const float* __restrict__ home,   const float* __restrict__ cs,
    const float* __restrict__ masses, const float* __restrict__ tens,
    const float* __restrict__ mics,   float* __restrict__ out)
{
    __shared__ __align__(16) float sbuf[16][1280];   // 80 KB wave-local staging
    __shared__ __align__(16) float lRec[2][8192];    // 64 KB rec accumulators
    __shared__ float2 qcL[2][64];
    __shared__ float2 s0cL[2][64];

    int bm   = blockIdx.x;
    int tid  = threadIdx.x;
    int half = tid >> 9;
    int wl   = (tid >> 6) & 7;      // wave within half
    int lane = tid & 63;
    int w    = tid & 511;           // window index within chain
    int sub  = w & 7;
    int chunk = w >> 3;
    int m    = bm & (MM - 1);

    float csm = cs[m];
    float ms  = masses[m];

    float* sb = sbuf[tid >> 6];
    int wp = (lane >> 2) * 20 + (lane & 3) * 4;

    // prologue loads for it=0 (chain d = half)
    float4 lf[4], lh[4];
    {
        size_t gb = (size_t)(bm * DD + half) * NS + wl * 1024;
#pragma unroll
        for (int i = 0; i < 4; ++i) {
            lf[i] = *(const float4*)(forces + gb + i * 256 + 4 * lane);
            lh[i] = *(const float4*)(hm + gb + i * 256 + 4 * lane);
        }
    }

    for (int it = 0; it < 4; ++it) {
        int dcur = 2 * it + half;
        float k   = tens[m * DD + dcur] / ms;
        float hd  = home[dcur];
        float mm_ = ms * mics[m * DD + dcur];
        size_t gbase = (size_t)(bm * DD + dcur) * NS + wl * 1024;

        // wave-local transpose: f then h (compiler orders via lgkmcnt)
#pragma unroll
        for (int i = 0; i < 4; ++i) *(float4*)(sb + wp + i * 320) = lf[i];
        float4 fq[4];
#pragma unroll
        for (int q = 0; q < 4; ++q)
            fq[q] = *(const float4*)(sb + lane * 20 + 4 * q);
#pragma unroll
        for (int i = 0; i < 4; ++i) *(float4*)(sb + wp + i * 320) = lh[i];
        float4 hq[4];
#pragma unroll
        for (int q = 0; q < 4; ++q)
            hq[q] = *(const float4*)(sb + lane * 20 + 4 * q);

        // prefetch next chain (hidden under scan + rewalk)
        if (it < 3) {
            size_t gn = (size_t)(bm * DD + 2 * (it + 1) + half) * NS + wl * 1024;
#pragma unroll
            for (int i = 0; i < 4; ++i) {
                lf[i] = *(const float4*)(forces + gn + i * 256 + 4 * lane);
                lh[i] = *(const float4*)(hm + gn + i * 256 + 4 * lane);
            }
        }

        const float* fr = (const float*)fq;
        const float* hr = (const float*)hq;

        // pass 1: zero-state forced response of this window
        float pos = 0.f, vel = 0.f;
#pragma unroll
        for (int i = 0; i < 16; ++i) {
            float ht  = fmaf(hr[i], csm, hd);
            float dir = ht - pos;
            float acc = fmaf(k, dir, fr[i]);
            vel = (vel + acc) * DAMP;
            pos += vel;
        }
        float Wx = pos, Wy = vel;

        // f32 matrices
        Mat A   = {1.f - DAMP * k, DAMP, -DAMP * k, DAMP};
        Mat A2  = matmul(A, A);
        Mat A4  = matmul(A2, A2);
        Mat A8  = matmul(A4, A4);
        Mat M0  = matmul(A8, A8);      // A^16
        Mat M1  = matmul(M0, M0);      // A^32
        Mat M2  = matmul(M1, M1);      // A^64
        Mat P = {1.f, 0.f, 0.f, 1.f};  // (A^16)^sub
        if (sub & 1) P = matmul(P, M0);
        if (sub & 2) P = matmul(P, M1);
        if (sub & 4) P = matmul(P, M2);

        // octet Kogge-Stone (f32), same math as R5-R7
        {
            float ox, oy;
            ox = __shfl_up(Wx, 1, 64); oy = __shfl_up(Wy, 1, 64);
            if (sub >= 1) { float nx = Wx + fmaf(M0.a, ox, M0.b * oy);
                            float ny = Wy + fmaf(M0.c, ox, M0.d * oy);
                            Wx = nx; Wy = ny; }
            ox = __shfl_up(Wx, 2, 64); oy = __shfl_up(Wy, 2, 64);
            if (sub >= 2) { float nx = Wx + fmaf(M1.a, ox, M1.b * oy);
                            float ny = Wy + fmaf(M1.c, ox, M1.d * oy);
                            Wx = nx; Wy = ny; }
            ox = __shfl_up(Wx, 4, 64); oy = __shfl_up(Wy, 4, 64);
            if (sub >= 4) { float nx = Wx + fmaf(M2.a, ox, M2.b * oy);
                            float ny = Wy + fmaf(M2.c, ox, M2.d * oy);
                            Wx = nx; Wy = ny; }
        }
        float Ex = __shfl_up(Wx, 1, 64);
        float Ey = __shfl_up(Wy, 1, 64);
        if (sub == 0) { Ex = 0.f; Ey = 0.f; }
        if (sub == 7) qcL[half][chunk] = make_float2(Wx, Wy);  // chunk response

        __syncthreads();

        // chunk scan (replaces phaseB): f64 KS across 64 chunks, wave 0 of half
        if (wl == 0) {
            double kd = (double)k;
            double dm = (double)DAMP;
            MatD B = {1.0 - dm * kd, dm, -dm * kd, dm};
#pragma unroll
            for (int i = 0; i < 7; ++i) B = matmuld(B, B);   // A^128
            float2 qv = qcL[half][lane];
            double sx = (double)qv.x, sy = (double)qv.y;
            MatD Kr = B;
#pragma unroll
            for (int r = 0; r < 6; ++r) {
                double ox = __shfl_up(sx, 1 << r, 64);
                double oy = __shfl_up(sy, 1 << r, 64);
                if (lane >= (1 << r)) {
                    double nx = fma(Kr.a, ox, fma(Kr.b, oy, sx));
                    double ny = fma(Kr.c, ox, fma(Kr.d, oy, sy));
                    sx = nx; sy = ny;
                }
                if (r < 5) Kr = matmuld(Kr, Kr);
            }
            double px = __shfl_up(sx, 1, 64);
            double py = __shfl_up(sy, 1, 64);
            if (lane == 0) { px = 0.0; py = 0.0; }
            s0cL[half][lane] = make_float2((float)px, (float)py);
        }
        __syncthreads();

        // rebase + exact re-walk
        float2 s0v = s0cL[half][chunk];
        pos = fmaf(P.a, s0v.x, fmaf(P.b, s0v.y, Ex));
        vel = fmaf(P.c, s0v.x, fmaf(P.d, s0v.y, Ey));

#pragma unroll
        for (int q = 0; q < 4; ++q) {
            float dv[4], rv[4];
#pragma unroll
            for (int i = 0; i < 4; ++i) {
                float ff = fr[q * 4 + i], hh = hr[q * 4 + i];
                float ht  = fmaf(hh, csm, hd);
                float dir = ht - pos;
                float acc = fmaf(k, dir, ff);
                vel = (vel + acc) * DAMP;
                pos += vel;
                dv[i] = dir;
                rv[i] = mm_ * acc;
            }
            *(float4*)(sb + lane * 20 + 4 * q) =
                make_float4(dv[0], dv[1], dv[2], dv[3]);
            int ps = P_SWZ(w * 16 + 4 * q);
            if (it == 0) {
                *(float4*)(&lRec[half][ps]) =
                    make_float4(rv[0], rv[1], rv[2], rv[3]);
            } else {
                float4 o = *(const float4*)(&lRec[half][ps]);
                *(float4*)(&lRec[half][ps]) =
                    make_float4(o.x + rv[0], o.y + rv[1],
                                o.z + rv[2], o.w + rv[3]);
            }
        }
        // flush disp coalesced (wave-local readback)
#pragma unroll
        for (int i = 0; i < 4; ++i) {
            float4 v = *(const float4*)(sb + wp + i * 320);
            *(float4*)(out + DISP_OFF + gbase + i * 256 + 4 * lane) = v;
        }
    }

    __syncthreads();
    // rec = lRec[0] + lRec[1], coalesced
#pragma unroll
    for (int j = 0; j < 2; ++j) {
        int x = j * 4096 + tid * 4;
        float4 a = *(const float4*)(&lRec[0][P_SWZ(x)]);
        float4 b = *(const float4*)(&lRec[1][P_SWZ(x)]);
        *(float4*)(out + REC_OFF + (size_t)bm * NS + x) =
            make_float4(a.x + b.x, a.y + b.y, a.z + b.z, a.w + b.w);
    }
}

// ---------------- HF kernel: noise + combined 256-tap FIR + lf add ----------
__global__ __launch_bounds__(256) void hf_kernel(
    const float* __restrict__ rec,
    const float* __restrict__ filters, const float* __restrict__ tfm,
    const float* __restrict__ bias,    const float* __restrict__ hf_gain,
    float* __restrict__ hf)
{
    __shared__ float up[SW(FL + SEG) + 8];
    __shared__ float gtap[FL];
    int bm  = blockIdx.x >> 2;
    int seg = blockIdx.x & 3;
    int b = bm >> 6;
    int m = bm & 63;
    int tx = threadIdx.x;
    int T0 = seg * SEG;

    float gs = 0.f;
#pragma unroll
    for (int f = 0; f < NF; ++f) {
        float mix = 0.f;
#pragma unroll
        for (int dd = 0; dd < DD; ++dd)
            mix = fmaf(bias[m * DD + dd], tfm[(m * DD + dd) * NF + f], mix);
        gs = fmaf(mix, filters[(b * NF + f) * FL + tx], gs);
    }
    gtap[tx] = gs;

    const float* rrow = rec + (size_t)bm * NS;
    for (int j = tx; j < FL + SEG; j += 256) {
        int t = T0 - FL + j;
        float v = 0.f;
        if (t >= 0) v = fabsf(rrow[t]) * jax_noise((unsigned)(bm * NS + t));
        up[SW(j)] = v;
    }
    __syncthreads();

    float gain = hf_gain[0];
    float* hrow = hf + (size_t)bm * NS;
    int t0 = tx * 8;
    float acc[8] = {0, 0, 0, 0, 0, 0, 0, 0};
    float w[8];
#pragma unroll
    for (int j = 0; j < 8; ++j) w[j] = up[SW(t0 + 1 + j)];
#pragma unroll 8
    for (int s = 255; s >= 1; --s) {
        float gv = gtap[s];
#pragma unroll
        for (int j = 0; j < 8; ++j) acc[j] = fmaf(gv, w[j], acc[j]);
#pragma unroll
        for (int j = 0; j < 7; ++j) w[j] = w[j + 1];
        w[7] = up[SW(FL + t0 + 8 - s)];
    }
    float g0 = gtap[0];
#pragma unroll
    for (int j = 0; j < 8; ++j) acc[j] = fmaf(g0, w[j], acc[j]);
    float4 r0 = *(const float4*)(rrow + T0 + t0);
    float4 r1 = *(const float4*)(rrow + T0 + t0 + 4);
    float4 o0 = make_float4(fmaf(gain, acc[0], r0.x), fmaf(gain, acc[1], r0.y),
                            fmaf(gain, acc[2], r0.z), fmaf(gain, acc[3], r0.w));
    float4 o1 = make_float4(fmaf(gain, acc[4], r1.x), fmaf(gain, acc[5], r1.y),
                            fmaf(gain, acc[6], r1.z), fmaf(gain, acc[7], r1.w));
    *(float4*)(hrow + T0 + t0)     = o0;
    *(float4*)(hrow + T0 + t0 + 4) = o1;
}

extern "C" void kernel_launch(void* const* d_in, const int* in_sizes, int n_in,
                              void* d_out, int out_size, void* d_ws, size_t ws_size,
                              hipStream_t stream)
{
    const float* forces  = (const float*)d_in[0];
    const float* hm      = (const float*)d_in[1];
    const float* filters = (const float*)d_in[2];
    const float* home    = (const float*)d_in[3];
    const float* cs      = (const float*)d_in[4];
    const float* masses  = (const float*)d_in[5];
    const float* tens    = (const float*)d_in[6];
    const float* mics    = (const float*)d_in[7];
    const float* tfm     = (const float*)d_in[8];
    const float* bias    = (const float*)d_in[9];
    const float* gain    = (const float*)d_in[10];
    float* out = (float*)d_out;

    sim_fused<<<BB * MM, 1024, 0, stream>>>(
        forces, hm, home, cs, masses, tens, mics, out);
    hf_kernel<<<BB * MM * 4, 256, 0, stream>>>(
        out + REC_OFF, filters, tfm, bias, gain, out + HF_OFF);
}

// Round 9
// 102.318 us; speedup vs baseline: 1.2072x; 1.2072x over previous
//
#include <hip/hip_runtime.h>

// ---------------------------------------------------------------------------
// BetterGooLayer R9: fused sim, parallelism fixed.
// R8 post-mortem: the invariant ~50us "phaseA" time was the harness poison-
// fill's 327MB L2->HBM writeback draining during our first kernel (WRITE_SIZE
// 197MB vs 75MB own). Fusion (read inputs once, hide reads under drain) is
// right; R8 failed on 1 block/CU lockstep. R9: block = (bm, chain-pair):
// 1024 independent blocks x 512 thr, 73KB LDS -> 2 blocks/CU. rec becomes
// 4 partial rows in d_ws (deterministic); hf sums partials + writes rec.
// Window math / octet f32 KS / in-block f64 chunk scan identical to R8.
// ---------------------------------------------------------------------------

#define NS    8192
#define BB    4
#define MM    64
#define DD    8
#define NF    8
#define FL    256
#define CHUNKS 64
#define DAMP  0.9998f
#define SEG   2048

#define REC_OFF  0
#define DISP_OFF (BB*MM*NS)                 // 2097152
#define HF_OFF   (DISP_OFF + BB*MM*DD*NS)   // 18874368

#define SW(i) ((i) + ((i) >> 5))
#define P_SWZ(p) (((p) & ~15) | (((((p) >> 2) ^ ((p) >> 5)) & 3) << 2) | ((p) & 3))

struct Mat { float a, b, c, d; };
__device__ __forceinline__ Mat matmul(Mat x, Mat y) {
    Mat r;
    r.a = fmaf(x.a, y.a, x.b * y.c);
    r.b = fmaf(x.a, y.b, x.b * y.d);
    r.c = fmaf(x.c, y.a, x.d * y.c);
    r.d = fmaf(x.c, y.b, x.d * y.d);
    return r;
}
struct MatD { double a, b, c, d; };
__device__ __forceinline__ MatD matmuld(MatD x, MatD y) {
    MatD r;
    r.a = fma(x.a, y.a, x.b * y.c);
    r.b = fma(x.a, y.b, x.b * y.d);
    r.c = fma(x.c, y.a, x.d * y.c);
    r.d = fma(x.c, y.b, x.d * y.d);
    return r;
}

// ---------------- threefry2x32 (JAX, partitionable counters) ----------------
__device__ __forceinline__ unsigned rotl32(unsigned x, int r) {
    return (x << r) | (x >> (32 - r));
}
__device__ float jax_noise(unsigned idx) {
    const unsigned ks0 = 0u;
    const unsigned ks1 = 123u;
    const unsigned ks2 = 0x1BD11BDAu ^ 0u ^ 123u;
    unsigned x0 = 0u  + ks0;
    unsigned x1 = idx + ks1;
#define TF_RND(r) { x0 += x1; x1 = rotl32(x1, r); x1 ^= x0; }
    TF_RND(13) TF_RND(15) TF_RND(26) TF_RND(6)
    x0 += ks1; x1 += ks2 + 1u;
    TF_RND(17) TF_RND(29) TF_RND(16) TF_RND(24)
    x0 += ks2; x1 += ks0 + 2u;
    TF_RND(13) TF_RND(15) TF_RND(26) TF_RND(6)
    x0 += ks0; x1 += ks1 + 3u;
    TF_RND(17) TF_RND(29) TF_RND(16) TF_RND(24)
    x0 += ks1; x1 += ks2 + 4u;
    TF_RND(13) TF_RND(15) TF_RND(26) TF_RND(6)
    x0 += ks2; x1 += ks0 + 5u;
#undef TF_RND
    unsigned bits = x0 ^ x1;
    float u = __uint_as_float((bits >> 9) | 0x3f800000u) - 1.0f;  // [0,1)
    return fmaxf(-0.01f, u * 0.02f - 0.01f);
}

// ---------------- fused sim: block = (bm, pair), 512 threads ----------------
// Chains d = 2p, 2p+1 over 2 iterations. Per chain: wave-local transpose ->
// 16-step window walk -> octet f32 KS -> f64 chunk KS (wave 0) -> re-walk.
// Partial rec (sum of the 2 chains) -> d_ws row (bm*4+p).
__global__ __launch_bounds__(512, 4) void sim_fused(
    const float* __restrict__ forces, const float* __restrict__ hm,
    const float* __restrict__ home,   const float* __restrict__ cs,
    const float* __restrict__ masses, const float* __restrict__ tens,
    const float* __restrict__ mics,   float* __restrict__ out,
    float* __restrict__ part)
{
    __shared__ __align__(16) float sbuf[8][1280];   // 40 KB wave-local staging
    __shared__ __align__(16) float lRec[8192];      // 32 KB partial rec
    __shared__ float2 qcL[64];
    __shared__ float2 s0cL[64];

    int bm   = blockIdx.x >> 2;
    int p    = blockIdx.x & 3;
    int tid  = threadIdx.x;
    int wl   = tid >> 6;
    int lane = tid & 63;
    int w    = tid;                 // window index within chain
    int sub  = lane & 7;
    int chunk = w >> 3;             // = wl*8 + (lane>>3)
    int m    = bm & (MM - 1);

    float csm = cs[m];
    float ms  = masses[m];

    float* sb = sbuf[wl];
    int wp = (lane >> 2) * 20 + (lane & 3) * 4;

    // prologue loads for chain d = 2p
    float4 lf[4], lh[4];
    {
        size_t gb = (size_t)(bm * DD + 2 * p) * NS + wl * 1024;
#pragma unroll
        for (int i = 0; i < 4; ++i) {
            lf[i] = *(const float4*)(forces + gb + i * 256 + 4 * lane);
            lh[i] = *(const float4*)(hm + gb + i * 256 + 4 * lane);
        }
    }

    for (int it = 0; it < 2; ++it) {
        int dcur = 2 * p + it;
        float k   = tens[m * DD + dcur] / ms;
        float hd  = home[dcur];
        float mm_ = ms * mics[m * DD + dcur];
        size_t gbase = (size_t)(bm * DD + dcur) * NS + wl * 1024;

        // wave-local transpose: f then h (within-wave lgkmcnt ordering)
#pragma unroll
        for (int i = 0; i < 4; ++i) *(float4*)(sb + wp + i * 320) = lf[i];
        float4 fq[4];
#pragma unroll
        for (int q = 0; q < 4; ++q)
            fq[q] = *(const float4*)(sb + lane * 20 + 4 * q);
#pragma unroll
        for (int i = 0; i < 4; ++i) *(float4*)(sb + wp + i * 320) = lh[i];
        float4 hq[4];
#pragma unroll
        for (int q = 0; q < 4; ++q)
            hq[q] = *(const float4*)(sb + lane * 20 + 4 * q);

        // prefetch second chain (hidden under scan + rewalk)
        if (it == 0) {
            size_t gn = (size_t)(bm * DD + 2 * p + 1) * NS + wl * 1024;
#pragma unroll
            for (int i = 0; i < 4; ++i) {
                lf[i] = *(const float4*)(forces + gn + i * 256 + 4 * lane);
                lh[i] = *(const float4*)(hm + gn + i * 256 + 4 * lane);
            }
        }

        const float* fr = (const float*)fq;
        const float* hr = (const float*)hq;

        // pass 1: zero-state forced response of this window
        float pos = 0.f, vel = 0.f;
#pragma unroll
        for (int i = 0; i < 16; ++i) {
            float ht  = fmaf(hr[i], csm, hd);
            float dir = ht - pos;
            float acc = fmaf(k, dir, fr[i]);
            vel = (vel + acc) * DAMP;
            pos += vel;
        }
        float Wx = pos, Wy = vel;

        Mat A   = {1.f - DAMP * k, DAMP, -DAMP * k, DAMP};
        Mat A2  = matmul(A, A);
        Mat A4  = matmul(A2, A2);
        Mat A8  = matmul(A4, A4);
        Mat M0  = matmul(A8, A8);      // A^16
        Mat M1  = matmul(M0, M0);      // A^32
        Mat M2  = matmul(M1, M1);      // A^64
        Mat P = {1.f, 0.f, 0.f, 1.f};  // (A^16)^sub
        if (sub & 1) P = matmul(P, M0);
        if (sub & 2) P = matmul(P, M1);
        if (sub & 4) P = matmul(P, M2);

        // octet Kogge-Stone (f32)
        {
            float ox, oy;
            ox = __shfl_up(Wx, 1, 64); oy = __shfl_up(Wy, 1, 64);
            if (sub >= 1) { float nx = Wx + fmaf(M0.a, ox, M0.b * oy);
                            float ny = Wy + fmaf(M0.c, ox, M0.d * oy);
                            Wx = nx; Wy = ny; }
            ox = __shfl_up(Wx, 2, 64); oy = __shfl_up(Wy, 2, 64);
            if (sub >= 2) { float nx = Wx + fmaf(M1.a, ox, M1.b * oy);
                            float ny = Wy + fmaf(M1.c, ox, M1.d * oy);
                            Wx = nx; Wy = ny; }
            ox = __shfl_up(Wx, 4, 64); oy = __shfl_up(Wy, 4, 64);
            if (sub >= 4) { float nx = Wx + fmaf(M2.a, ox, M2.b * oy);
                            float ny = Wy + fmaf(M2.c, ox, M2.d * oy);
                            Wx = nx; Wy = ny; }
        }
        float Ex = __shfl_up(Wx, 1, 64);
        float Ey = __shfl_up(Wy, 1, 64);
        if (sub == 0) { Ex = 0.f; Ey = 0.f; }
        if (sub == 7) qcL[chunk] = make_float2(Wx, Wy);

        __syncthreads();

        // f64 Kogge-Stone over 64 chunks (wave 0)
        if (wl == 0) {
            double kd = (double)k;
            double dm = (double)DAMP;
            MatD B = {1.0 - dm * kd, dm, -dm * kd, dm};
#pragma unroll
            for (int i = 0; i < 7; ++i) B = matmuld(B, B);   // A^128
            float2 qv = qcL[lane];
            double sx = (double)qv.x, sy = (double)qv.y;
            MatD Kr = B;
#pragma unroll
            for (int r = 0; r < 6; ++r) {
                double ox = __shfl_up(sx, 1 << r, 64);
                double oy = __shfl_up(sy, 1 << r, 64);
                if (lane >= (1 << r)) {
                    double nx = fma(Kr.a, ox, fma(Kr.b, oy, sx));
                    double ny = fma(Kr.c, ox, fma(Kr.d, oy, sy));
                    sx = nx; sy = ny;
                }
                if (r < 5) Kr = matmuld(Kr, Kr);
            }
            double px = __shfl_up(sx, 1, 64);
            double py = __shfl_up(sy, 1, 64);
            if (lane == 0) { px = 0.0; py = 0.0; }
            s0cL[lane] = make_float2((float)px, (float)py);
        }
        __syncthreads();

        // rebase + exact re-walk
        float2 s0v = s0cL[chunk];
        pos = fmaf(P.a, s0v.x, fmaf(P.b, s0v.y, Ex));
        vel = fmaf(P.c, s0v.x, fmaf(P.d, s0v.y, Ey));

#pragma unroll
        for (int q = 0; q < 4; ++q) {
            float dv[4], rv[4];
#pragma unroll
            for (int i = 0; i < 4; ++i) {
                float ff = fr[q * 4 + i], hh = hr[q * 4 + i];
                float ht  = fmaf(hh, csm, hd);
                float dir = ht - pos;
                float acc = fmaf(k, dir, ff);
                vel = (vel + acc) * DAMP;
                pos += vel;
                dv[i] = dir;
                rv[i] = mm_ * acc;
            }
            *(float4*)(sb + lane * 20 + 4 * q) =
                make_float4(dv[0], dv[1], dv[2], dv[3]);
            int ps = P_SWZ(w * 16 + 4 * q);
            if (it == 0) {
                *(float4*)(&lRec[ps]) =
                    make_float4(rv[0], rv[1], rv[2], rv[3]);
            } else {
                float4 o = *(const float4*)(&lRec[ps]);
                *(float4*)(&lRec[ps]) =
                    make_float4(o.x + rv[0], o.y + rv[1],
                                o.z + rv[2], o.w + rv[3]);
            }
        }
        // flush disp coalesced (wave-local readback)
#pragma unroll
        for (int i = 0; i < 4; ++i) {
            float4 v = *(const float4*)(sb + wp + i * 320);
            *(float4*)(out + DISP_OFF + gbase + i * 256 + 4 * lane) = v;
        }
    }

    __syncthreads();
    // write partial rec row, coalesced
    float* prow = part + (size_t)(bm * 4 + p) * NS;
#pragma unroll
    for (int j = 0; j < 4; ++j) {
        int x = j * 2048 + tid * 4;
        float4 v = *(const float4*)(&lRec[P_SWZ(x)]);
        *(float4*)(prow + x) = v;
    }
}

// ---------------- HF kernel: partial-sum + noise + FIR + rec/hf write -------
// Grid 1024 = 256 (b,m) x 4 segments of 2048.
__global__ __launch_bounds__(256) void hf_kernel(
    const float* __restrict__ part,
    const float* __restrict__ filters, const float* __restrict__ tfm,
    const float* __restrict__ bias,    const float* __restrict__ hf_gain,
    float* __restrict__ out)
{
    __shared__ float up[SW(FL + SEG) + 8];
    __shared__ float recL[SEG];
    __shared__ float gtap[FL];
    int bm  = blockIdx.x >> 2;
    int seg = blockIdx.x & 3;
    int b = bm >> 6;
    int m = bm & 63;
    int tx = threadIdx.x;
    int T0 = seg * SEG;

    float gs = 0.f;
#pragma unroll
    for (int f = 0; f < NF; ++f) {
        float mix = 0.f;
#pragma unroll
        for (int dd = 0; dd < DD; ++dd)
            mix = fmaf(bias[m * DD + dd], tfm[(m * DD + dd) * NF + f], mix);
        gs = fmaf(mix, filters[(b * NF + f) * FL + tx], gs);
    }
    gtap[tx] = gs;

    const float* p0 = part + (size_t)(bm * 4 + 0) * NS;
    const float* p1 = part + (size_t)(bm * 4 + 1) * NS;
    const float* p2 = part + (size_t)(bm * 4 + 2) * NS;
    const float* p3 = part + (size_t)(bm * 4 + 3) * NS;
    for (int j = tx; j < FL + SEG; j += 256) {
        int t = T0 - FL + j;
        float v = 0.f, r = 0.f;
        if (t >= 0) {
            r = (p0[t] + p1[t]) + (p2[t] + p3[t]);
            v = fabsf(r) * jax_noise((unsigned)(bm * NS + t));
        }
        up[SW(j)] = v;
        if (j >= FL) recL[j - FL] = r;
    }
    __syncthreads();

    float gain = hf_gain[0];
    int t0 = tx * 8;
    float acc[8] = {0, 0, 0, 0, 0, 0, 0, 0};
    float w[8];
#pragma unroll
    for (int j = 0; j < 8; ++j) w[j] = up[SW(t0 + 1 + j)];
#pragma unroll 8
    for (int s = 255; s >= 1; --s) {
        float gv = gtap[s];
#pragma unroll
        for (int j = 0; j < 8; ++j) acc[j] = fmaf(gv, w[j], acc[j]);
#pragma unroll
        for (int j = 0; j < 7; ++j) w[j] = w[j + 1];
        w[7] = up[SW(FL + t0 + 8 - s)];
    }
    float g0 = gtap[0];
#pragma unroll
    for (int j = 0; j < 8; ++j) acc[j] = fmaf(g0, w[j], acc[j]);
    float4 r0 = *(const float4*)(&recL[t0]);
    float4 r1 = *(const float4*)(&recL[t0 + 4]);
    float4 o0 = make_float4(fmaf(gain, acc[0], r0.x), fmaf(gain, acc[1], r0.y),
                            fmaf(gain, acc[2], r0.z), fmaf(gain, acc[3], r0.w));
    float4 o1 = make_float4(fmaf(gain, acc[4], r1.x), fmaf(gain, acc[5], r1.y),
                            fmaf(gain, acc[6], r1.z), fmaf(gain, acc[7], r1.w));
    size_t rowoff = (size_t)bm * NS + T0 + t0;
    *(float4*)(out + HF_OFF + rowoff)     = o0;
    *(float4*)(out + HF_OFF + rowoff + 4) = o1;
    *(float4*)(out + REC_OFF + rowoff)     = r0;   // rec output
    *(float4*)(out + REC_OFF + rowoff + 4) = r1;
}

extern "C" void kernel_launch(void* const* d_in, const int* in_sizes, int n_in,
                              void* d_out, int out_size, void* d_ws, size_t ws_size,
                              hipStream_t stream)
{
    const float* forces  = (const float*)d_in[0];
    const float* hm      = (const float*)d_in[1];
    const float* filters = (const float*)d_in[2];
    const float* home    = (const float*)d_in[3];
    const float* cs      = (const float*)d_in[4];
    const float* masses  = (const float*)d_in[5];
    const float* tens    = (const float*)d_in[6];
    const float* mics    = (const float*)d_in[7];
    const float* tfm     = (const float*)d_in[8];
    const float* bias    = (const float*)d_in[9];
    const float* gain    = (const float*)d_in[10];
    float* out = (float*)d_out;

    float* part = (float*)d_ws;    // 1024 rows x 8192 floats = 32 MiB

    sim_fused<<<BB * MM * 4, 512, 0, stream>>>(
        forces, hm, home, cs, masses, tens, mics, out, part);
    hf_kernel<<<BB * MM * 4, 256, 0, stream>>>(
        part, filters, tfm, bias, gain, out);
}

// Round 10
// 90.719 us; speedup vs baseline: 1.3616x; 1.1279x over previous
//
#include <hip/hip_runtime.h>

// ---------------------------------------------------------------------------
// BetterGooLayer R10: one chain per block, occupancy-first fused sim.
// R9 post-mortem: 85us at 3.1 TB/s, occ 35% — latency-bound from 2 blocks/CU
// + per-chain barriers. R10: grid 2048 = (bm,d), 512 thr, LDS 41KB ->
// 3 blocks/CU; h stays in LDS (re-read in both walks), rewalk overwrites each
// h-slot with dv (no extra LDS); rv flushed per chain to d_ws partial rows;
// f64 chunk scan done redundantly by every wave (shuffle broadcast) -> ONE
// barrier per block, no wave0 serialization. Target VGPR<=64 (8 waves/SIMD).
// hf sums 8 partials while staging. Math identical to R9 (absmax ~8).
// ---------------------------------------------------------------------------

#define NS    8192
#define BB    4
#define MM    64
#define DD    8
#define NF    8
#define FL    256
#define DAMP  0.9998f
#define SEG   2048

#define REC_OFF  0
#define DISP_OFF (BB*MM*NS)                 // 2097152
#define HF_OFF   (DISP_OFF + BB*MM*DD*NS)   // 18874368

#define SW(i) ((i) + ((i) >> 5))

struct Mat { float a, b, c, d; };
__device__ __forceinline__ Mat matmul(Mat x, Mat y) {
    Mat r;
    r.a = fmaf(x.a, y.a, x.b * y.c);
    r.b = fmaf(x.a, y.b, x.b * y.d);
    r.c = fmaf(x.c, y.a, x.d * y.c);
    r.d = fmaf(x.c, y.b, x.d * y.d);
    return r;
}
struct MatD { double a, b, c, d; };
__device__ __forceinline__ MatD matmuld(MatD x, MatD y) {
    MatD r;
    r.a = fma(x.a, y.a, x.b * y.c);
    r.b = fma(x.a, y.b, x.b * y.d);
    r.c = fma(x.c, y.a, x.d * y.c);
    r.d = fma(x.c, y.b, x.d * y.d);
    return r;
}

// ---------------- threefry2x32 (JAX, partitionable counters) ----------------
__device__ __forceinline__ unsigned rotl32(unsigned x, int r) {
    return (x << r) | (x >> (32 - r));
}
__device__ float jax_noise(unsigned idx) {
    const unsigned ks0 = 0u;
    const unsigned ks1 = 123u;
    const unsigned ks2 = 0x1BD11BDAu ^ 0u ^ 123u;
    unsigned x0 = 0u  + ks0;
    unsigned x1 = idx + ks1;
#define TF_RND(r) { x0 += x1; x1 = rotl32(x1, r); x1 ^= x0; }
    TF_RND(13) TF_RND(15) TF_RND(26) TF_RND(6)
    x0 += ks1; x1 += ks2 + 1u;
    TF_RND(17) TF_RND(29) TF_RND(16) TF_RND(24)
    x0 += ks2; x1 += ks0 + 2u;
    TF_RND(13) TF_RND(15) TF_RND(26) TF_RND(6)
    x0 += ks0; x1 += ks1 + 3u;
    TF_RND(17) TF_RND(29) TF_RND(16) TF_RND(24)
    x0 += ks1; x1 += ks2 + 4u;
    TF_RND(13) TF_RND(15) TF_RND(26) TF_RND(6)
    x0 += ks2; x1 += ks0 + 5u;
#undef TF_RND
    unsigned bits = x0 ^ x1;
    float u = __uint_as_float((bits >> 9) | 0x3f800000u) - 1.0f;  // [0,1)
    return fmaxf(-0.01f, u * 0.02f - 0.01f);
}

// ---------------- fused sim: block = (bm,d) chain, 512 threads --------------
__global__ __launch_bounds__(512, 8) void sim_fused(
    const float* __restrict__ forces, const float* __restrict__ hm,
    const float* __restrict__ home,   const float* __restrict__ cs,
    const float* __restrict__ masses, const float* __restrict__ tens,
    const float* __restrict__ mics,   float* __restrict__ out,
    float* __restrict__ part)
{
    __shared__ __align__(16) float sbuf[8][1280];   // 40 KB wave-local
    __shared__ float2 qcL[64];

    int bmd  = blockIdx.x;          // bm*8 + d
    int bm   = bmd >> 3;
    int d    = bmd & 7;
    int tid  = threadIdx.x;
    int wl   = tid >> 6;
    int lane = tid & 63;
    int sub  = lane & 7;
    int m    = bm & (MM - 1);

    float ms  = masses[m];
    float k   = tens[m * DD + d] / ms;
    float csm = cs[m];
    float hd  = home[d];
    float mm_ = ms * mics[m * DD + d];

    float* sb = sbuf[wl];
    int wp = (lane >> 2) * 20 + (lane & 3) * 4;
    size_t gbase = (size_t)bmd * NS + wl * 1024;

    // issue all 8 coalesced loads up front
    float4 t0 = *(const float4*)(forces + gbase +   0 + 4 * lane);
    float4 t1 = *(const float4*)(forces + gbase + 256 + 4 * lane);
    float4 t2 = *(const float4*)(forces + gbase + 512 + 4 * lane);
    float4 t3 = *(const float4*)(forces + gbase + 768 + 4 * lane);
    float4 u0 = *(const float4*)(hm + gbase +   0 + 4 * lane);
    float4 u1 = *(const float4*)(hm + gbase + 256 + 4 * lane);
    float4 u2 = *(const float4*)(hm + gbase + 512 + 4 * lane);
    float4 u3 = *(const float4*)(hm + gbase + 768 + 4 * lane);

    // transpose forces -> registers
    *(float4*)(sb + wp +   0) = t0;
    *(float4*)(sb + wp + 320) = t1;
    *(float4*)(sb + wp + 640) = t2;
    *(float4*)(sb + wp + 960) = t3;
    float4 fq[4];
#pragma unroll
    for (int q = 0; q < 4; ++q)
        fq[q] = *(const float4*)(sb + lane * 20 + 4 * q);
    // transpose hm -> stays in LDS (read during both walks)
    *(float4*)(sb + wp +   0) = u0;
    *(float4*)(sb + wp + 320) = u1;
    *(float4*)(sb + wp + 640) = u2;
    *(float4*)(sb + wp + 960) = u3;

    const float* fr = (const float*)fq;

    // pass 1: zero-state forced response of this 16-step window
    float pos = 0.f, vel = 0.f;
#pragma unroll
    for (int q = 0; q < 4; ++q) {
        float4 hv = *(const float4*)(sb + lane * 20 + 4 * q);
        float hh[4] = {hv.x, hv.y, hv.z, hv.w};
#pragma unroll
        for (int i = 0; i < 4; ++i) {
            float ht  = fmaf(hh[i], csm, hd);
            float dir = ht - pos;
            float acc = fmaf(k, dir, fr[q * 4 + i]);
            vel = (vel + acc) * DAMP;
            pos += vel;
        }
    }
    float Wx = pos, Wy = vel;

    Mat A   = {1.f - DAMP * k, DAMP, -DAMP * k, DAMP};
    Mat A2  = matmul(A, A);
    Mat A4  = matmul(A2, A2);
    Mat A8  = matmul(A4, A4);
    Mat M0  = matmul(A8, A8);      // A^16
    Mat M1  = matmul(M0, M0);      // A^32
    Mat M2  = matmul(M1, M1);      // A^64
    Mat P = {1.f, 0.f, 0.f, 1.f};  // (A^16)^sub
    if (sub & 1) P = matmul(P, M0);
    if (sub & 2) P = matmul(P, M1);
    if (sub & 4) P = matmul(P, M2);

    // octet Kogge-Stone (f32) within 8-lane groups
    {
        float ox, oy;
        ox = __shfl_up(Wx, 1, 64); oy = __shfl_up(Wy, 1, 64);
        if (sub >= 1) { float nx = Wx + fmaf(M0.a, ox, M0.b * oy);
                        float ny = Wy + fmaf(M0.c, ox, M0.d * oy);
                        Wx = nx; Wy = ny; }
        ox = __shfl_up(Wx, 2, 64); oy = __shfl_up(Wy, 2, 64);
        if (sub >= 2) { float nx = Wx + fmaf(M1.a, ox, M1.b * oy);
                        float ny = Wy + fmaf(M1.c, ox, M1.d * oy);
                        Wx = nx; Wy = ny; }
        ox = __shfl_up(Wx, 4, 64); oy = __shfl_up(Wy, 4, 64);
        if (sub >= 4) { float nx = Wx + fmaf(M2.a, ox, M2.b * oy);
                        float ny = Wy + fmaf(M2.c, ox, M2.d * oy);
                        Wx = nx; Wy = ny; }
    }
    float Ex = __shfl_up(Wx, 1, 64);
    float Ey = __shfl_up(Wy, 1, 64);
    if (sub == 0) { Ex = 0.f; Ey = 0.f; }
    if (sub == 7) qcL[tid >> 3] = make_float2(Wx, Wy);

    __syncthreads();   // the ONLY block barrier

    // f64 chunk scan, redundantly in every wave (lane = chunk)
    float s0x, s0y;
    {
        double kd = (double)k;
        double dm = (double)DAMP;
        MatD B = {1.0 - dm * kd, dm, -dm * kd, dm};
#pragma unroll
        for (int i = 0; i < 7; ++i) B = matmuld(B, B);   // A^128
        float2 qv = qcL[lane];
        double sx = (double)qv.x, sy = (double)qv.y;
        MatD Kr = B;
#pragma unroll
        for (int r = 0; r < 6; ++r) {
            double ox = __shfl_up(sx, 1 << r, 64);
            double oy = __shfl_up(sy, 1 << r, 64);
            if (lane >= (1 << r)) {
                double nx = fma(Kr.a, ox, fma(Kr.b, oy, sx));
                double ny = fma(Kr.c, ox, fma(Kr.d, oy, sy));
                sx = nx; sy = ny;
            }
            if (r < 5) Kr = matmuld(Kr, Kr);
        }
        // broadcast: this thread's chunk start = inclusive value of chunk-1
        int srcl = (tid >> 3) - 1;
        double px = __shfl(sx, srcl & 63, 64);
        double py = __shfl(sy, srcl & 63, 64);
        if (srcl < 0) { px = 0.0; py = 0.0; }
        s0x = (float)px; s0y = (float)py;
    }

    // rebase + exact re-walk; dv overwrites h slots in-place
    pos = fmaf(P.a, s0x, fmaf(P.b, s0y, Ex));
    vel = fmaf(P.c, s0x, fmaf(P.d, s0y, Ey));

    float rv[16];
#pragma unroll
    for (int q = 0; q < 4; ++q) {
        float4 hv = *(const float4*)(sb + lane * 20 + 4 * q);
        float hh[4] = {hv.x, hv.y, hv.z, hv.w};
        float dv[4];
#pragma unroll
        for (int i = 0; i < 4; ++i) {
            float ht  = fmaf(hh[i], csm, hd);
            float dir = ht - pos;
            float acc = fmaf(k, dir, fr[q * 4 + i]);
            vel = (vel + acc) * DAMP;
            pos += vel;
            dv[i] = dir;
            rv[q * 4 + i] = mm_ * acc;
        }
        *(float4*)(sb + lane * 20 + 4 * q) =
            make_float4(dv[0], dv[1], dv[2], dv[3]);   // same slot as hv
    }
    // flush disp coalesced
#pragma unroll
    for (int i = 0; i < 4; ++i) {
        float4 v = *(const float4*)(sb + wp + i * 320);
        *(float4*)(out + DISP_OFF + gbase + i * 256 + 4 * lane) = v;
    }
    // stage rv rows, flush partial rec coalesced
#pragma unroll
    for (int q = 0; q < 4; ++q)
        *(float4*)(sb + lane * 20 + 4 * q) =
            make_float4(rv[q * 4], rv[q * 4 + 1], rv[q * 4 + 2], rv[q * 4 + 3]);
#pragma unroll
    for (int i = 0; i < 4; ++i) {
        float4 v = *(const float4*)(sb + wp + i * 320);
        *(float4*)(part + gbase + i * 256 + 4 * lane) = v;
    }
}

// ---------------- HF kernel: 8-partial sum + noise + FIR + rec/hf write -----
// Grid 1024 = 256 (b,m) x 4 segments of 2048.
__global__ __launch_bounds__(256) void hf_kernel(
    const float* __restrict__ part,
    const float* __restrict__ filters, const float* __restrict__ tfm,
    const float* __restrict__ bias,    const float* __restrict__ hf_gain,
    float* __restrict__ out)
{
    __shared__ float up[SW(FL + SEG) + 8];
    __shared__ float recL[SEG];
    __shared__ float gtap[FL];
    int bm  = blockIdx.x >> 2;
    int seg = blockIdx.x & 3;
    int b = bm >> 6;
    int m = bm & 63;
    int tx = threadIdx.x;
    int T0 = seg * SEG;

    float gs = 0.f;
#pragma unroll
    for (int f = 0; f < NF; ++f) {
        float mix = 0.f;
#pragma unroll
        for (int dd = 0; dd < DD; ++dd)
            mix = fmaf(bias[m * DD + dd], tfm[(m * DD + dd) * NF + f], mix);
        gs = fmaf(mix, filters[(b * NF + f) * FL + tx], gs);
    }
    gtap[tx] = gs;

    const float* pb = part + (size_t)(bm * DD) * NS;
    for (int j = tx; j < FL + SEG; j += 256) {
        int t = T0 - FL + j;
        float v = 0.f, r = 0.f;
        if (t >= 0) {
            r = ((pb[t] + pb[t + NS]) + (pb[t + 2 * NS] + pb[t + 3 * NS]))
              + ((pb[t + 4 * NS] + pb[t + 5 * NS])
               + (pb[t + 6 * NS] + pb[t + 7 * NS]));
            v = fabsf(r) * jax_noise((unsigned)(bm * NS + t));
        }
        up[SW(j)] = v;
        if (j >= FL) recL[j - FL] = r;
    }
    __syncthreads();

    float gain = hf_gain[0];
    int t0 = tx * 8;
    float acc[8] = {0, 0, 0, 0, 0, 0, 0, 0};
    float w[8];
#pragma unroll
    for (int j = 0; j < 8; ++j) w[j] = up[SW(t0 + 1 + j)];
#pragma unroll 8
    for (int s = 255; s >= 1; --s) {
        float gv = gtap[s];
#pragma unroll
        for (int j = 0; j < 8; ++j) acc[j] = fmaf(gv, w[j], acc[j]);
#pragma unroll
        for (int j = 0; j < 7; ++j) w[j] = w[j + 1];
        w[7] = up[SW(FL + t0 + 8 - s)];
    }
    float g0 = gtap[0];
#pragma unroll
    for (int j = 0; j < 8; ++j) acc[j] = fmaf(g0, w[j], acc[j]);
    float4 r0 = *(const float4*)(&recL[t0]);
    float4 r1 = *(const float4*)(&recL[t0 + 4]);
    float4 o0 = make_float4(fmaf(gain, acc[0], r0.x), fmaf(gain, acc[1], r0.y),
                            fmaf(gain, acc[2], r0.z), fmaf(gain, acc[3], r0.w));
    float4 o1 = make_float4(fmaf(gain, acc[4], r1.x), fmaf(gain, acc[5], r1.y),
                            fmaf(gain, acc[6], r1.z), fmaf(gain, acc[7], r1.w));
    size_t rowoff = (size_t)bm * NS + T0 + t0;
    *(float4*)(out + HF_OFF + rowoff)     = o0;
    *(float4*)(out + HF_OFF + rowoff + 4) = o1;
    *(float4*)(out + REC_OFF + rowoff)     = r0;
    *(float4*)(out + REC_OFF + rowoff + 4) = r1;
}

extern "C" void kernel_launch(void* const* d_in, const int* in_sizes, int n_in,
                              void* d_out, int out_size, void* d_ws, size_t ws_size,
                              hipStream_t stream)
{
    const float* forces  = (const float*)d_in[0];
    const float* hm      = (const float*)d_in[1];
    const float* filters = (const float*)d_in[2];
    const float* home    = (const float*)d_in[3];
    const float* cs      = (const float*)d_in[4];
    const float* masses  = (const float*)d_in[5];
    const float* tens    = (const float*)d_in[6];
    const float* mics    = (const float*)d_in[7];
    const float* tfm     = (const float*)d_in[8];
    const float* bias    = (const float*)d_in[9];
    const float* gain    = (const float*)d_in[10];
    float* out = (float*)d_out;

    float* part = (float*)d_ws;    // 2048 rows x 8192 floats = 64 MiB

    sim_fused<<<BB * MM * DD, 512, 0, stream>>>(
        forces, hm, home, cs, masses, tens, mics, out, part);
    hf_kernel<<<BB * MM * 4, 256, 0, stream>>>(
        part, filters, tfm, bias, gain, out);
}